// Round 5
// baseline (1198.494 us; speedup 1.0000x reference)
//
#include <hip/hip_runtime.h>

// V=10000, R=8192, D=1024, B=1024, L=64, M=65536
// R14 = R12 (1069 us) + k_step BK=256 rewrite.
// R13 post-mortem: moving load-issue after barrier(2) was a no-op/perturbation
// (compiler can sink load issue past s_barrier anyway; implicit vmcnt(0) only
// covers loads issued before the barrier in the FINAL schedule) -> k_mlp/k_xw
// reverted to R12's measured-better ordering.
// R14 theory: RNN phase (~495 us) is barrier-cadence bound: R13 k_step wave
// does 4 MFMA per barrier-pair (vs k_mlp's 32), 32 barriers/step. BK=256
// (k_step has 1 block/CU -> no occupancy cost; LDS 82 KB) gives 8
// barriers/step and 16 MFMA/wave/chunk. Swizzle generalized to 32-slot rows:
// slot' = (slot&24)|((slot^(row&7))&7), bijective, even bank-group spread on
// write and read. Predicted: ~7.7 -> ~5 us/step, total ~1092 -> ~900.
#define D_DIM   1024
#define L_SEQ   64
#define B_BATCH 1024
#define M_NODES 65536
#define R_RULES 8192
#define V_VOCAB 10000

typedef unsigned short bf16_t;
typedef __attribute__((ext_vector_type(8))) short s8v;   // 8 bf16 (MFMA A/B frag)
typedef __attribute__((ext_vector_type(4))) short s4v;   // 4 bf16
typedef __attribute__((ext_vector_type(4))) float f4v;   // MFMA C/D frag

static __device__ __forceinline__ float bf2f(unsigned short u) {
    union { unsigned int i; float f; } v; v.i = ((unsigned int)u) << 16; return v.f;
}
static __device__ __forceinline__ unsigned short f2bf(float f) {  // RNE
    union { float f; unsigned int i; } v; v.f = f;
    return (unsigned short)((v.i + 0x7FFFu + ((v.i >> 16) & 1u)) >> 16);
}
static __device__ __forceinline__ float fast_tanh(float x) {
    float xc = fminf(fmaxf(x, -15.f), 15.f);
    float t  = __expf(2.f * xc);
    return (t - 1.f) * __builtin_amdgcn_rcpf(t + 1.f);
}

static __device__ __forceinline__ f4v mfma16(s8v a, s8v b, f4v c) {
    return __builtin_amdgcn_mfma_f32_16x16x32_bf16(a, b, c, 0, 0, 0);
}

// ---------------------------------------------------------------------------
__global__ __launch_bounds__(256) void k_cvt_emb(
    const float* __restrict__ emb, bf16_t* __restrict__ embB)
{
    size_t i = ((size_t)blockIdx.x * 256 + threadIdx.x) * 8;
    f4v x0 = *(const f4v*)&emb[i];
    f4v x1 = *(const f4v*)&emb[i + 4];
    s8v o;
    o[0] = (short)f2bf(x0.x); o[1] = (short)f2bf(x0.y);
    o[2] = (short)f2bf(x0.z); o[3] = (short)f2bf(x0.w);
    o[4] = (short)f2bf(x1.x); o[5] = (short)f2bf(x1.y);
    o[6] = (short)f2bf(x1.z); o[7] = (short)f2bf(x1.w);
    *(s8v*)&embB[i] = o;
}

__global__ __launch_bounds__(256) void k_transcvt(
    const float* __restrict__ src, bf16_t* __restrict__ dst, int K, int N)
{
    __shared__ float s[32][33];
    int n0 = blockIdx.x * 32, k0 = blockIdx.y * 32;
    int tx = threadIdx.x, ty = threadIdx.y;  // (32,8)
#pragma unroll
    for (int i = 0; i < 4; ++i)
        s[ty + i * 8][tx] = src[(size_t)(k0 + ty + i * 8) * N + n0 + tx];
    __syncthreads();
#pragma unroll
    for (int i = 0; i < 4; ++i)
        dst[(size_t)(n0 + ty + i * 8) * K + k0 + tx] = f2bf(s[tx][ty + i * 8]);
}

__global__ __launch_bounds__(256) void k_cvt_h0(
    const float* __restrict__ h0, bf16_t* __restrict__ h0b)
{
    for (int u = threadIdx.x; u < D_DIM; u += 256) h0b[u] = f2bf(h0[u]);
}

// ---------------------------------------------------------------------------
// k_xw_mfma: XE[n,:] = bf16(embB[tokens[n],:] @ Wxh + bh)
// 128x128 tile, BK=64, swizzled LDS, R12 load placement, XCD swizzle.
// ---------------------------------------------------------------------------
__global__ __launch_bounds__(256) void k_xw_mfma(
    const int* __restrict__ tokens, const bf16_t* __restrict__ embB,
    const bf16_t* __restrict__ WxhT, const float* __restrict__ bh,
    bf16_t* __restrict__ XE)
{
    __shared__ bf16_t As[128 * 64];            // 16 KB (swizzled 16B slots)
    __shared__ bf16_t Bs[128 * 64];            // 16 KB
    __shared__ float  epi[4][16][68];          // 17.4 KB (per-wave private)

    const int bi  = blockIdx.x;
    const int xcd = bi & 7, j = bi >> 3;
    const int row0 = ((xcd << 6) + (j >> 3)) * 128;   // rowTile in [0,512)
    const int col0 = (j & 7) * 128;                   // colTile in [0,8)

    const int tid = threadIdx.x;
    const int w = tid >> 6, l = tid & 63;
    const int q = l >> 4, t16 = l & 15;
    const int wm = (w >> 1) * 64, wn = (w & 1) * 64;

    const int rr = tid >> 2, c0 = tid & 3;            // staging row / base slot
    const int sw0 = ((c0       ^ (rr & 7)) << 3);     // swizzled slot offsets
    const int sw1 = (((c0 + 4) ^ (rr & 7)) << 3);     // ((rr+64)&7)==(rr&7)

    const bf16_t* arow[2];
#pragma unroll
    for (int r = 0; r < 2; ++r)
        arow[r] = embB + (size_t)tokens[row0 + rr + r * 64] * D_DIM + c0 * 8;
    const bf16_t* brow[2];
#pragma unroll
    for (int r = 0; r < 2; ++r)
        brow[r] = WxhT + (size_t)(col0 + rr + r * 64) * D_DIM + c0 * 8;

    f4v acc[4][4];
#pragma unroll
    for (int i = 0; i < 4; ++i)
#pragma unroll
        for (int jj = 0; jj < 4; ++jj) acc[i][jj] = (f4v)0.f;

    // prefetch chunk 0 (8 x 16B)
    s8v a00 = *(const s8v*)(arow[0]);
    s8v a01 = *(const s8v*)(arow[0] + 32);
    s8v a10 = *(const s8v*)(arow[1]);
    s8v a11 = *(const s8v*)(arow[1] + 32);
    s8v b00 = *(const s8v*)(brow[0]);
    s8v b01 = *(const s8v*)(brow[0] + 32);
    s8v b10 = *(const s8v*)(brow[1]);
    s8v b11 = *(const s8v*)(brow[1] + 32);

    const int r7 = t16 & 7;
    for (int k0 = 0; k0 < D_DIM; k0 += 64) {
        __syncthreads();                       // prev iter frag reads done
        *(s8v*)&As[rr * 64 + sw0]        = a00;
        *(s8v*)&As[rr * 64 + sw1]        = a01;
        *(s8v*)&As[(rr + 64) * 64 + sw0] = a10;
        *(s8v*)&As[(rr + 64) * 64 + sw1] = a11;
        *(s8v*)&Bs[rr * 64 + sw0]        = b00;
        *(s8v*)&Bs[rr * 64 + sw1]        = b01;
        *(s8v*)&Bs[(rr + 64) * 64 + sw0] = b10;
        *(s8v*)&Bs[(rr + 64) * 64 + sw1] = b11;
        int kn = k0 + 64;
        if (kn < D_DIM) {                      // issue next loads
            a00 = *(const s8v*)(arow[0] + kn);
            a01 = *(const s8v*)(arow[0] + kn + 32);
            a10 = *(const s8v*)(arow[1] + kn);
            a11 = *(const s8v*)(arow[1] + kn + 32);
            b00 = *(const s8v*)(brow[0] + kn);
            b01 = *(const s8v*)(brow[0] + kn + 32);
            b10 = *(const s8v*)(brow[1] + kn);
            b11 = *(const s8v*)(brow[1] + kn + 32);
        }
        __syncthreads();
#pragma unroll
        for (int sub = 0; sub < 2; ++sub) {
            const int rsl = (((sub * 4 + q) ^ r7) << 3);
            s8v af[4], bfr[4];
#pragma unroll
            for (int ti = 0; ti < 4; ++ti)
                af[ti] = *(const s8v*)&As[(wm + ti * 16 + t16) * 64 + rsl];
#pragma unroll
            for (int tj = 0; tj < 4; ++tj)
                bfr[tj] = *(const s8v*)&Bs[(wn + tj * 16 + t16) * 64 + rsl];
#pragma unroll
            for (int ti = 0; ti < 4; ++ti)
#pragma unroll
                for (int tj = 0; tj < 4; ++tj)
                    acc[ti][tj] = mfma16(af[ti], bfr[tj], acc[ti][tj]);
        }
    }

    // barrier-free per-wave epilogue (epi[w] wave-private)
    const int lr = l >> 2, c16 = (l & 3) * 16;
    f4v bias[4];
#pragma unroll
    for (int u = 0; u < 4; ++u)
        bias[u] = *(const f4v*)&bh[col0 + wn + c16 + u * 4];
#pragma unroll
    for (int ti = 0; ti < 4; ++ti) {
#pragma unroll
        for (int tj = 0; tj < 4; ++tj)
#pragma unroll
            for (int rg = 0; rg < 4; ++rg)
                epi[w][q * 4 + rg][tj * 16 + t16] = acc[ti][tj][rg];
        s8v o0, o1;
#pragma unroll
        for (int u = 0; u < 8; ++u) {
            o0[u] = (short)f2bf(epi[w][lr][c16 + u]     + bias[u >> 2][u & 3]);
            o1[u] = (short)f2bf(epi[w][lr][c16 + 8 + u] + bias[2 + (u >> 2)][u & 3]);
        }
        size_t orow = (size_t)(row0 + wm + ti * 16 + lr) * D_DIM + col0 + wn + c16;
        *(s8v*)&XE[orow]     = o0;
        *(s8v*)&XE[orow + 8] = o1;
    }
}

// ---------------------------------------------------------------------------
// k_step_mfma (x64): y = tanh(XE[b*L+t,:] + h_prev[b,:] @ Whh); XE[..] = bf16(y)
// 64x64 tile, 512 threads, 4x2 wave split (16x32/wave), BK=256 (4 chunks,
// 8 barriers/step, 16 MFMA/wave/chunk), 32-slot-row XOR swizzle, 1 block/CU.
// ---------------------------------------------------------------------------
__global__ __launch_bounds__(512) void k_step_mfma(
    const bf16_t* __restrict__ Abase, int strideRow,
    const bf16_t* __restrict__ WhhT, bf16_t* __restrict__ XE, int t)
{
    __shared__ bf16_t As[64 * 256];            // 32 KB
    __shared__ bf16_t Bs[64 * 256];            // 32 KB
    __shared__ float  epi[8][16][36];          // 18.4 KB (per-wave private)

    const int tid = threadIdx.x;
    const int w = tid >> 6, l = tid & 63;
    const int q = l >> 4, t16 = l & 15;
    const int wr = w & 3, wc = w >> 2;         // 4x2: 16 rows x 32 cols per wave
    const int row0 = blockIdx.x * 64, col0 = blockIdx.y * 64;

    const int rr = tid >> 3, c0 = tid & 7;     // 64 rows x 8 base slots (of 32)
    const int swb = ((c0 ^ (rr & 7)) << 3);    // swizzled elem offset, group 0

    const bf16_t* asrc = Abase + (size_t)(row0 + rr) * strideRow + c0 * 8;
    const bf16_t* bsrc = WhhT + (size_t)(col0 + rr) * D_DIM + c0 * 8;

    f4v acc[2];
    acc[0] = (f4v)0.f; acc[1] = (f4v)0.f;

    s8v pa[4], pb[4];
#pragma unroll
    for (int kk = 0; kk < 4; ++kk) {
        pa[kk] = *(const s8v*)(asrc + kk * 64);
        pb[kk] = *(const s8v*)(bsrc + kk * 64);
    }

    const int r7 = t16 & 7;
    for (int k0 = 0; k0 < D_DIM; k0 += 256) {
        __syncthreads();                       // prev chunk frag reads done
#pragma unroll
        for (int kk = 0; kk < 4; ++kk) {
            *(s8v*)&As[rr * 256 + kk * 64 + swb] = pa[kk];
            *(s8v*)&Bs[rr * 256 + kk * 64 + swb] = pb[kk];
        }
        int kn = k0 + 256;
        if (kn < D_DIM) {
#pragma unroll
            for (int kk = 0; kk < 4; ++kk) {
                pa[kk] = *(const s8v*)(asrc + kn + kk * 64);
                pb[kk] = *(const s8v*)(bsrc + kn + kk * 64);
            }
        }
        __syncthreads();
#pragma unroll
        for (int sub = 0; sub < 8; ++sub) {
            const int slot = sub * 4 + q;                        // [0,32)
            const int rsl  = ((slot & 24) | ((slot ^ r7) & 7)) << 3;
            s8v af = *(const s8v*)&As[(wr * 16 + t16) * 256 + rsl];
            s8v b0 = *(const s8v*)&Bs[(wc * 32 + t16) * 256 + rsl];
            s8v b1 = *(const s8v*)&Bs[(wc * 32 + 16 + t16) * 256 + rsl];
            acc[0] = mfma16(af, b0, acc[0]);
            acc[1] = mfma16(af, b1, acc[1]);
        }
    }

    // per-wave epilogue, no barriers: 16 rows x 32 cols per wave
    const int lr = l >> 2, c8 = (l & 3) * 8;
#pragma unroll
    for (int tj = 0; tj < 2; ++tj)
#pragma unroll
        for (int rg = 0; rg < 4; ++rg)
            epi[w][q * 4 + rg][tj * 16 + t16] = acc[tj][rg];
    f4v v0 = *(const f4v*)&epi[w][lr][c8];
    f4v v1 = *(const f4v*)&epi[w][lr][c8 + 4];
    int b = row0 + wr * 16 + lr;
    size_t xi = ((size_t)b * L_SEQ + t) * D_DIM + col0 + wc * 32 + c8;
    s8v x = *(const s8v*)&XE[xi];
    s8v o;
#pragma unroll
    for (int u = 0; u < 4; ++u) {
        o[u]     = (short)f2bf(fast_tanh(bf2f((unsigned short)x[u])     + v0[u]));
        o[u + 4] = (short)f2bf(fast_tanh(bf2f((unsigned short)x[u + 4]) + v1[u]));
    }
    *(s8v*)&XE[xi] = o;
}

// ---------------------------------------------------------------------------
// k_mlp_mfma: h = tanh(concat(XE[i],XE[j]) @ W1 + b1) fused with rule-dot.
// 128x128 tile, K=2048, BK=64, swizzled LDS, R12 load placement, XCD swizzle.
// ---------------------------------------------------------------------------
__global__ __launch_bounds__(256) void k_mlp_mfma(
    const int* __restrict__ i_idx, const int* __restrict__ j_idx,
    const bf16_t* __restrict__ XE, const bf16_t* __restrict__ W1T,
    const float* __restrict__ b1, const bf16_t* __restrict__ Wt2,
    const int* __restrict__ r_idx, float* __restrict__ partials)
{
    __shared__ bf16_t As[128 * 64];            // 16 KB
    __shared__ bf16_t Bs[128 * 64];            // 16 KB

    const int bi  = blockIdx.x;
    const int xcd = bi & 7, j = bi >> 3;
    const int rowTile = (xcd << 6) + (j >> 3);        // [0,512)
    const int colTile = j & 7;                        // [0,8)
    const int row0 = rowTile * 128, col0 = colTile * 128;

    const int tid = threadIdx.x;
    const int w = tid >> 6, l = tid & 63;
    const int q = l >> 4, t16 = l & 15;
    const int wm = (w >> 1) * 64, wn = (w & 1) * 64;

    const int rr = tid >> 2, c0 = tid & 3;
    const int sw0 = ((c0       ^ (rr & 7)) << 3);
    const int sw1 = (((c0 + 4) ^ (rr & 7)) << 3);

    const bf16_t* pi[2]; const bf16_t* pj[2];
#pragma unroll
    for (int r = 0; r < 2; ++r) {
        int m = row0 + rr + r * 64;
        pi[r] = XE + (size_t)i_idx[m] * D_DIM + c0 * 8;
        pj[r] = XE + (size_t)j_idx[m] * D_DIM - D_DIM + c0 * 8;  // k in [1024,2048)
    }
    const bf16_t* brow[2];
#pragma unroll
    for (int r = 0; r < 2; ++r)
        brow[r] = W1T + (size_t)(col0 + rr + r * 64) * (2 * D_DIM) + c0 * 8;

    f4v acc[4][4];
#pragma unroll
    for (int i = 0; i < 4; ++i)
#pragma unroll
        for (int jj = 0; jj < 4; ++jj) acc[i][jj] = (f4v)0.f;

    // prefetch chunk 0
    s8v a00 = *(const s8v*)(pi[0]);
    s8v a01 = *(const s8v*)(pi[0] + 32);
    s8v a10 = *(const s8v*)(pi[1]);
    s8v a11 = *(const s8v*)(pi[1] + 32);
    s8v b00 = *(const s8v*)(brow[0]);
    s8v b01 = *(const s8v*)(brow[0] + 32);
    s8v b10 = *(const s8v*)(brow[1]);
    s8v b11 = *(const s8v*)(brow[1] + 32);

    const int r7 = t16 & 7;
    for (int k0 = 0; k0 < 2 * D_DIM; k0 += 64) {
        __syncthreads();
        *(s8v*)&As[rr * 64 + sw0]        = a00;
        *(s8v*)&As[rr * 64 + sw1]        = a01;
        *(s8v*)&As[(rr + 64) * 64 + sw0] = a10;
        *(s8v*)&As[(rr + 64) * 64 + sw1] = a11;
        *(s8v*)&Bs[rr * 64 + sw0]        = b00;
        *(s8v*)&Bs[rr * 64 + sw1]        = b01;
        *(s8v*)&Bs[(rr + 64) * 64 + sw0] = b10;
        *(s8v*)&Bs[(rr + 64) * 64 + sw1] = b11;
        int kn = k0 + 64;
        if (kn < 2 * D_DIM) {
            const bf16_t* A0 = (kn < D_DIM) ? pi[0] : pj[0];
            const bf16_t* A1 = (kn < D_DIM) ? pi[1] : pj[1];
            a00 = *(const s8v*)(A0 + kn);
            a01 = *(const s8v*)(A0 + kn + 32);
            a10 = *(const s8v*)(A1 + kn);
            a11 = *(const s8v*)(A1 + kn + 32);
            b00 = *(const s8v*)(brow[0] + kn);
            b01 = *(const s8v*)(brow[0] + kn + 32);
            b10 = *(const s8v*)(brow[1] + kn);
            b11 = *(const s8v*)(brow[1] + kn + 32);
        }
        __syncthreads();
#pragma unroll
        for (int sub = 0; sub < 2; ++sub) {
            const int rsl = (((sub * 4 + q) ^ r7) << 3);
            s8v af[4], bfr[4];
#pragma unroll
            for (int ti = 0; ti < 4; ++ti)
                af[ti] = *(const s8v*)&As[(wm + ti * 16 + t16) * 64 + rsl];
#pragma unroll
            for (int tj = 0; tj < 4; ++tj)
                bfr[tj] = *(const s8v*)&Bs[(wn + tj * 16 + t16) * 64 + rsl];
#pragma unroll
            for (int ti = 0; ti < 4; ++ti)
#pragma unroll
                for (int tj = 0; tj < 4; ++tj)
                    acc[ti][tj] = mfma16(af[ti], bfr[tj], acc[ti][tj]);
        }
    }

    // fused epilogue in C-layout: fast_tanh, dot with gathered rule row, 16-lane reduce
    const int cb = colTile * 2 + (w & 1);
#pragma unroll
    for (int ti = 0; ti < 4; ++ti) {
#pragma unroll
        for (int rg = 0; rg < 4; ++rg) {
            int m = row0 + wm + ti * 16 + q * 4 + rg;
            int r = r_idx[m];
            const bf16_t* wrow = Wt2 + (size_t)r * D_DIM + col0 + wn + t16;
            float pd = 0.f;
#pragma unroll
            for (int tj = 0; tj < 4; ++tj) {
                int col = col0 + wn + tj * 16 + t16;
                float h = fast_tanh(acc[ti][tj][rg] + b1[col]);
                pd += h * bf2f(wrow[tj * 16]);
            }
            pd += __shfl_xor(pd, 1);
            pd += __shfl_xor(pd, 2);
            pd += __shfl_xor(pd, 4);
            pd += __shfl_xor(pd, 8);
            if (t16 == 0)
                partials[(size_t)cb * M_NODES + m] = pd;
        }
    }
}

// ---------------------------------------------------------------------------
__global__ __launch_bounds__(256) void k_reduce(
    const float* __restrict__ partials, const int* __restrict__ r_idx,
    const float* __restrict__ b2, float* __restrict__ out)
{
    int m = blockIdx.x * 256 + threadIdx.x;
    float s = 0.f;
#pragma unroll
    for (int cb = 0; cb < 16; ++cb)
        s += partials[(size_t)cb * M_NODES + m];
    out[m] = s + b2[r_idx[m]];
}

// ---------------------------------------------------------------------------
extern "C" void kernel_launch(void* const* d_in, const int* in_sizes, int n_in,
                              void* d_out, int out_size, void* d_ws, size_t ws_size,
                              hipStream_t stream) {
    const int*   tokens = (const int*)  d_in[0];
    const int*   i_idx  = (const int*)  d_in[1];
    const int*   j_idx  = (const int*)  d_in[2];
    const int*   r_idx  = (const int*)  d_in[3];
    const float* emb    = (const float*)d_in[4];
    const float* Wxh    = (const float*)d_in[5];
    const float* Whh    = (const float*)d_in[6];
    const float* bh     = (const float*)d_in[7];
    const float* h0     = (const float*)d_in[8];
    const float* W1     = (const float*)d_in[9];
    const float* b1     = (const float*)d_in[10];
    const float* W2     = (const float*)d_in[11];
    const float* b2     = (const float*)d_in[12];
    float* out = (float*)d_out;

    // Workspace (~156 MiB). embB (20 MiB) aliases WhhT/W1T/Wt2 (22 MiB):
    // embB dead after k_xw_mfma; those conversions run after it.
    bf16_t* XE   = (bf16_t*)d_ws;                        // [B*L][D]  128 MiB
    bf16_t* WxhT = XE   + (size_t)M_NODES * D_DIM;       // [D][D]      2 MiB
    bf16_t* WhhT = WxhT + (size_t)D_DIM * D_DIM;         // [D][D]      2 MiB
    bf16_t* W1T  = WhhT + (size_t)D_DIM * D_DIM;         // [D][2D]     4 MiB
    bf16_t* Wt2  = W1T  + (size_t)2 * D_DIM * D_DIM;     // [R][D]     16 MiB
    bf16_t* embB = WhhT;                                 // [V][D]     20 MiB (alias)
    bf16_t* h0b  = Wt2  + (size_t)R_RULES * D_DIM;       // [D] (pad 2048)
    float*  par  = (float*)(h0b + 2048);                 // [16][M]     4 MiB

    // Phase 1: emb->bf16, Wxh, h0
    k_cvt_emb<<<V_VOCAB * D_DIM / 2048, 256, 0, stream>>>(emb, embB);
    k_transcvt<<<dim3(D_DIM / 32, D_DIM / 32), dim3(32, 8), 0, stream>>>(Wxh, WxhT, D_DIM, D_DIM);
    k_cvt_h0<<<1, 256, 0, stream>>>(h0, h0b);

    // Phase 2: XE = bf16(embB[tokens] @ Wxh + bh)   (last reader of embB)
    k_xw_mfma<<<4096, 256, 0, stream>>>(tokens, embB, WxhT, bh, XE);

    // Phase 3: remaining weight conversions (overwrite embB region)
    k_transcvt<<<dim3(D_DIM / 32, D_DIM / 32), dim3(32, 8), 0, stream>>>(Whh, WhhT, D_DIM, D_DIM);
    k_transcvt<<<dim3(D_DIM / 32, 2 * D_DIM / 32), dim3(32, 8), 0, stream>>>(W1, W1T, 2 * D_DIM, D_DIM);
    k_transcvt<<<dim3(R_RULES / 32, D_DIM / 32), dim3(32, 8), 0, stream>>>(W2, Wt2, D_DIM, R_RULES);

    // Phase 4: 64 sequential RNN steps (in-place on XE)
    for (int t = 0; t < L_SEQ; ++t) {
        const bf16_t* Abase = (t == 0) ? h0b : (XE + (size_t)(t - 1) * D_DIM);
        int strideRow       = (t == 0) ? 0   : L_SEQ * D_DIM;
        k_step_mfma<<<dim3(B_BATCH / 64, D_DIM / 64), 512, 0, stream>>>(
            Abase, strideRow, WhhT, XE, t);
    }

    // Phase 5: MLP + fused rule-dot partials
    k_mlp_mfma<<<4096, 256, 0, stream>>>(
        i_idx, j_idx, XE, W1T, b1, Wt2, r_idx, par);

    // Phase 6: deterministic reduce + b2
    k_reduce<<<M_NODES / 256, 256, 0, stream>>>(par, r_idx, b2, out);
}

// Round 6
// 1102.644 us; speedup vs baseline: 1.0869x; 1.0869x over previous
//
#include <hip/hip_runtime.h>

// V=10000, R=8192, D=1024, B=1024, L=64, M=65536
// R15: (a) k_step reverted to R12's proven structure (256 thr, 2x2 quadrant
// 32x32 waves, BK=64) -- R14's BK=256 cost +110 us (82KB LDS -> 1 block/CU,
// monolithic staging burst serialized the gather latency into 4 big drains).
// (b) ALL three MFMA kernels now use a double-buffered LDS pipeline with ONE
// barrier per chunk: compute buf[c&1] -> ds_write chunk c+1 into buf[(c+1)&1]
// -> issue loads chunk c+2 -> barrier. WAR on buf[(c+1)&1] (iter c-1's
// readers) is covered by the iteration-end barrier; so is write visibility.
// Halves barriers (k_mlp 64->33) and gives every global load a full compute
// phase (~1400cy > ~900cy HBM gather) to land, with the vmcnt wait AFTER the
// MFMAs. Predicted: k_mlp 371->~300 (MfmaUtil 32->40), k_xw ~130, RNN ~430.
// Noise note: k_mlp identical code measured 371 (R12) vs 383 (R14) -> ~3%
// run-to-run variance; deltas under ~4% are noise.
#define D_DIM   1024
#define L_SEQ   64
#define B_BATCH 1024
#define M_NODES 65536
#define R_RULES 8192
#define V_VOCAB 10000

typedef unsigned short bf16_t;
typedef __attribute__((ext_vector_type(8))) short s8v;   // 8 bf16 (MFMA A/B frag)
typedef __attribute__((ext_vector_type(4))) short s4v;   // 4 bf16
typedef __attribute__((ext_vector_type(4))) float f4v;   // MFMA C/D frag

static __device__ __forceinline__ float bf2f(unsigned short u) {
    union { unsigned int i; float f; } v; v.i = ((unsigned int)u) << 16; return v.f;
}
static __device__ __forceinline__ unsigned short f2bf(float f) {  // RNE
    union { float f; unsigned int i; } v; v.f = f;
    return (unsigned short)((v.i + 0x7FFFu + ((v.i >> 16) & 1u)) >> 16);
}
static __device__ __forceinline__ float fast_tanh(float x) {
    float xc = fminf(fmaxf(x, -15.f), 15.f);
    float t  = __expf(2.f * xc);
    return (t - 1.f) * __builtin_amdgcn_rcpf(t + 1.f);
}

static __device__ __forceinline__ f4v mfma16(s8v a, s8v b, f4v c) {
    return __builtin_amdgcn_mfma_f32_16x16x32_bf16(a, b, c, 0, 0, 0);
}

// ---------------------------------------------------------------------------
__global__ __launch_bounds__(256) void k_cvt_emb(
    const float* __restrict__ emb, bf16_t* __restrict__ embB)
{
    size_t i = ((size_t)blockIdx.x * 256 + threadIdx.x) * 8;
    f4v x0 = *(const f4v*)&emb[i];
    f4v x1 = *(const f4v*)&emb[i + 4];
    s8v o;
    o[0] = (short)f2bf(x0.x); o[1] = (short)f2bf(x0.y);
    o[2] = (short)f2bf(x0.z); o[3] = (short)f2bf(x0.w);
    o[4] = (short)f2bf(x1.x); o[5] = (short)f2bf(x1.y);
    o[6] = (short)f2bf(x1.z); o[7] = (short)f2bf(x1.w);
    *(s8v*)&embB[i] = o;
}

__global__ __launch_bounds__(256) void k_transcvt(
    const float* __restrict__ src, bf16_t* __restrict__ dst, int K, int N)
{
    __shared__ float s[32][33];
    int n0 = blockIdx.x * 32, k0 = blockIdx.y * 32;
    int tx = threadIdx.x, ty = threadIdx.y;  // (32,8)
#pragma unroll
    for (int i = 0; i < 4; ++i)
        s[ty + i * 8][tx] = src[(size_t)(k0 + ty + i * 8) * N + n0 + tx];
    __syncthreads();
#pragma unroll
    for (int i = 0; i < 4; ++i)
        dst[(size_t)(n0 + ty + i * 8) * K + k0 + tx] = f2bf(s[tx][ty + i * 8]);
}

__global__ __launch_bounds__(256) void k_cvt_h0(
    const float* __restrict__ h0, bf16_t* __restrict__ h0b)
{
    for (int u = threadIdx.x; u < D_DIM; u += 256) h0b[u] = f2bf(h0[u]);
}

// ---------------------------------------------------------------------------
// k_xw_mfma: XE[n,:] = bf16(embB[tokens[n],:] @ Wxh + bh)
// 128x128 tile, BK=64, dbuf LDS / 1 barrier per chunk, XCD swizzle.
// ---------------------------------------------------------------------------
__global__ __launch_bounds__(256) void k_xw_mfma(
    const int* __restrict__ tokens, const bf16_t* __restrict__ embB,
    const bf16_t* __restrict__ WxhT, const float* __restrict__ bh,
    bf16_t* __restrict__ XE)
{
    __shared__ bf16_t As[2 * 128 * 64];        // 32 KB (dbuf, swizzled 16B slots)
    __shared__ bf16_t Bs[2 * 128 * 64];        // 32 KB
    __shared__ float  epi[4][16][68];          // 17.4 KB (per-wave private)

    const int bi  = blockIdx.x;
    const int xcd = bi & 7, j = bi >> 3;
    const int row0 = ((xcd << 6) + (j >> 3)) * 128;   // rowTile in [0,512)
    const int col0 = (j & 7) * 128;                   // colTile in [0,8)

    const int tid = threadIdx.x;
    const int w = tid >> 6, l = tid & 63;
    const int q = l >> 4, t16 = l & 15;
    const int wm = (w >> 1) * 64, wn = (w & 1) * 64;

    const int rr = tid >> 2, c0 = tid & 3;            // staging row / base slot
    const int sw0 = ((c0       ^ (rr & 7)) << 3);     // swizzled slot offsets
    const int sw1 = (((c0 + 4) ^ (rr & 7)) << 3);     // ((rr+64)&7)==(rr&7)

    const bf16_t* arow[2];
#pragma unroll
    for (int r = 0; r < 2; ++r)
        arow[r] = embB + (size_t)tokens[row0 + rr + r * 64] * D_DIM + c0 * 8;
    const bf16_t* brow[2];
#pragma unroll
    for (int r = 0; r < 2; ++r)
        brow[r] = WxhT + (size_t)(col0 + rr + r * 64) * D_DIM + c0 * 8;

    f4v acc[4][4];
#pragma unroll
    for (int i = 0; i < 4; ++i)
#pragma unroll
        for (int jj = 0; jj < 4; ++jj) acc[i][jj] = (f4v)0.f;

    s8v a00, a01, a10, a11, b00, b01, b10, b11;
    const int r7 = t16 & 7;

#define XW_LOAD(kn_)                                                          \
    {   const int kn = (kn_);                                                 \
        a00 = *(const s8v*)(arow[0] + kn);                                    \
        a01 = *(const s8v*)(arow[0] + kn + 32);                               \
        a10 = *(const s8v*)(arow[1] + kn);                                    \
        a11 = *(const s8v*)(arow[1] + kn + 32);                               \
        b00 = *(const s8v*)(brow[0] + kn);                                    \
        b01 = *(const s8v*)(brow[0] + kn + 32);                               \
        b10 = *(const s8v*)(brow[1] + kn);                                    \
        b11 = *(const s8v*)(brow[1] + kn + 32);                               \
    }
#define XW_WRITE(buf)                                                         \
    {   bf16_t* Aw = As + (buf) * 8192; bf16_t* Bw = Bs + (buf) * 8192;       \
        *(s8v*)&Aw[rr * 64 + sw0]        = a00;                               \
        *(s8v*)&Aw[rr * 64 + sw1]        = a01;                               \
        *(s8v*)&Aw[(rr + 64) * 64 + sw0] = a10;                               \
        *(s8v*)&Aw[(rr + 64) * 64 + sw1] = a11;                               \
        *(s8v*)&Bw[rr * 64 + sw0]        = b00;                               \
        *(s8v*)&Bw[rr * 64 + sw1]        = b01;                               \
        *(s8v*)&Bw[(rr + 64) * 64 + sw0] = b10;                               \
        *(s8v*)&Bw[(rr + 64) * 64 + sw1] = b11;                               \
    }

    XW_LOAD(0);
    XW_WRITE(0);
    XW_LOAD(64);
    __syncthreads();

    for (int c = 0; c < 16; ++c) {
        const bf16_t* Ar = As + (c & 1) * 8192;
        const bf16_t* Br = Bs + (c & 1) * 8192;
#pragma unroll
        for (int sub = 0; sub < 2; ++sub) {
            const int rsl = (((sub * 4 + q) ^ r7) << 3);
            s8v af[4], bfr[4];
#pragma unroll
            for (int ti = 0; ti < 4; ++ti)
                af[ti] = *(const s8v*)&Ar[(wm + ti * 16 + t16) * 64 + rsl];
#pragma unroll
            for (int tj = 0; tj < 4; ++tj)
                bfr[tj] = *(const s8v*)&Br[(wn + tj * 16 + t16) * 64 + rsl];
#pragma unroll
            for (int ti = 0; ti < 4; ++ti)
#pragma unroll
                for (int tj = 0; tj < 4; ++tj)
                    acc[ti][tj] = mfma16(af[ti], bfr[tj], acc[ti][tj]);
        }
        if (c < 15) XW_WRITE((c + 1) & 1);     // chunk c+1 regs -> other buffer
        if (c < 14) XW_LOAD((c + 2) * 64);     // issue chunk c+2
        __syncthreads();
    }
#undef XW_LOAD
#undef XW_WRITE

    // barrier-free per-wave epilogue (epi[w] wave-private)
    const int lr = l >> 2, c16 = (l & 3) * 16;
    f4v bias[4];
#pragma unroll
    for (int u = 0; u < 4; ++u)
        bias[u] = *(const f4v*)&bh[col0 + wn + c16 + u * 4];
#pragma unroll
    for (int ti = 0; ti < 4; ++ti) {
#pragma unroll
        for (int tj = 0; tj < 4; ++tj)
#pragma unroll
            for (int rg = 0; rg < 4; ++rg)
                epi[w][q * 4 + rg][tj * 16 + t16] = acc[ti][tj][rg];
        s8v o0, o1;
#pragma unroll
        for (int u = 0; u < 8; ++u) {
            o0[u] = (short)f2bf(epi[w][lr][c16 + u]     + bias[u >> 2][u & 3]);
            o1[u] = (short)f2bf(epi[w][lr][c16 + 8 + u] + bias[2 + (u >> 2)][u & 3]);
        }
        size_t orow = (size_t)(row0 + wm + ti * 16 + lr) * D_DIM + col0 + wn + c16;
        *(s8v*)&XE[orow]     = o0;
        *(s8v*)&XE[orow + 8] = o1;
    }
}

// ---------------------------------------------------------------------------
// k_step_mfma (x64): y = tanh(XE[b*L+t,:] + h_prev[b,:] @ Whh); XE[..] = bf16(y)
// R12 structure (best RNN): 64x64 tile, 256 thr, 2x2 quadrants of 32x32,
// BK=64, swizzle -- now with dbuf LDS / 1 barrier per chunk.
// ---------------------------------------------------------------------------
__global__ __launch_bounds__(256) void k_step_mfma(
    const bf16_t* __restrict__ Abase, int strideRow,
    const bf16_t* __restrict__ WhhT, bf16_t* __restrict__ XE, int t)
{
    __shared__ bf16_t As[2 * 64 * 64];         // 16 KB
    __shared__ bf16_t Bs[2 * 64 * 64];         // 16 KB
    __shared__ float  epi[4][16][36];          // 9.2 KB (per-wave private)

    const int tid = threadIdx.x;
    const int w = tid >> 6, l = tid & 63;
    const int q = l >> 4, t16 = l & 15;
    const int wr = w >> 1, wc = w & 1;         // 2x2 quadrants of 32x32
    const int row0 = blockIdx.x * 64, col0 = blockIdx.y * 64;

    const int rr = tid >> 2, c0 = tid & 3;
    const int sw0 = ((c0       ^ (rr & 7)) << 3);
    const int sw1 = (((c0 + 4) ^ (rr & 7)) << 3);

    const bf16_t* asrc = Abase + (size_t)(row0 + rr) * strideRow + c0 * 8;
    const bf16_t* bsrc = WhhT + (size_t)(col0 + rr) * D_DIM + c0 * 8;

    f4v acc[2][2];
#pragma unroll
    for (int i = 0; i < 2; ++i)
#pragma unroll
        for (int jj = 0; jj < 2; ++jj) acc[i][jj] = (f4v)0.f;

    s8v a0, a1, b0, b1;
    const int r7 = t16 & 7;

#define ST_LOAD(kn_)                                                          \
    {   const int kn = (kn_);                                                 \
        a0 = *(const s8v*)(asrc + kn);                                        \
        a1 = *(const s8v*)(asrc + kn + 32);                                   \
        b0 = *(const s8v*)(bsrc + kn);                                        \
        b1 = *(const s8v*)(bsrc + kn + 32);                                   \
    }
#define ST_WRITE(buf)                                                         \
    {   bf16_t* Aw = As + (buf) * 4096; bf16_t* Bw = Bs + (buf) * 4096;       \
        *(s8v*)&Aw[rr * 64 + sw0] = a0;                                       \
        *(s8v*)&Aw[rr * 64 + sw1] = a1;                                       \
        *(s8v*)&Bw[rr * 64 + sw0] = b0;                                       \
        *(s8v*)&Bw[rr * 64 + sw1] = b1;                                       \
    }

    ST_LOAD(0);
    ST_WRITE(0);
    ST_LOAD(64);
    __syncthreads();

    for (int c = 0; c < 16; ++c) {
        const bf16_t* Ar = As + (c & 1) * 4096;
        const bf16_t* Br = Bs + (c & 1) * 4096;
#pragma unroll
        for (int sub = 0; sub < 2; ++sub) {
            const int rsl = (((sub * 4 + q) ^ r7) << 3);
            s8v af[2], bfr[2];
#pragma unroll
            for (int ti = 0; ti < 2; ++ti)
                af[ti] = *(const s8v*)&Ar[(wr * 32 + ti * 16 + t16) * 64 + rsl];
#pragma unroll
            for (int tj = 0; tj < 2; ++tj)
                bfr[tj] = *(const s8v*)&Br[(wc * 32 + tj * 16 + t16) * 64 + rsl];
#pragma unroll
            for (int ti = 0; ti < 2; ++ti)
#pragma unroll
                for (int tj = 0; tj < 2; ++tj)
                    acc[ti][tj] = mfma16(af[ti], bfr[tj], acc[ti][tj]);
        }
        if (c < 15) ST_WRITE((c + 1) & 1);
        if (c < 14) ST_LOAD((c + 2) * 64);
        __syncthreads();
    }
#undef ST_LOAD
#undef ST_WRITE

    // per-wave epilogue, no barriers: transpose 16x32 per ti, add u_t, tanh
    const int lr = l >> 2, cg = l & 3;
#pragma unroll
    for (int ti = 0; ti < 2; ++ti) {
#pragma unroll
        for (int tj = 0; tj < 2; ++tj)
#pragma unroll
            for (int rg = 0; rg < 4; ++rg)
                epi[w][q * 4 + rg][tj * 16 + t16] = acc[ti][tj][rg];
        f4v v0 = *(const f4v*)&epi[w][lr][cg * 8];
        f4v v1 = *(const f4v*)&epi[w][lr][cg * 8 + 4];
        int b = row0 + wr * 32 + ti * 16 + lr;
        size_t xi = ((size_t)b * L_SEQ + t) * D_DIM + col0 + wc * 32 + cg * 8;
        s8v x = *(const s8v*)&XE[xi];
        s8v o;
#pragma unroll
        for (int u = 0; u < 4; ++u) {
            o[u]     = (short)f2bf(fast_tanh(bf2f((unsigned short)x[u])     + v0[u]));
            o[u + 4] = (short)f2bf(fast_tanh(bf2f((unsigned short)x[u + 4]) + v1[u]));
        }
        *(s8v*)&XE[xi] = o;
    }
}

// ---------------------------------------------------------------------------
// k_mlp_mfma: h = tanh(concat(XE[i],XE[j]) @ W1 + b1) fused with rule-dot.
// 128x128 tile, K=2048, BK=64, dbuf LDS / 1 barrier per chunk, XCD swizzle.
// ---------------------------------------------------------------------------
__global__ __launch_bounds__(256) void k_mlp_mfma(
    const int* __restrict__ i_idx, const int* __restrict__ j_idx,
    const bf16_t* __restrict__ XE, const bf16_t* __restrict__ W1T,
    const float* __restrict__ b1, const bf16_t* __restrict__ Wt2,
    const int* __restrict__ r_idx, float* __restrict__ partials)
{
    __shared__ bf16_t As[2 * 128 * 64];        // 32 KB
    __shared__ bf16_t Bs[2 * 128 * 64];        // 32 KB

    const int bi  = blockIdx.x;
    const int xcd = bi & 7, j = bi >> 3;
    const int rowTile = (xcd << 6) + (j >> 3);        // [0,512)
    const int colTile = j & 7;                        // [0,8)
    const int row0 = rowTile * 128, col0 = colTile * 128;

    const int tid = threadIdx.x;
    const int w = tid >> 6, l = tid & 63;
    const int q = l >> 4, t16 = l & 15;
    const int wm = (w >> 1) * 64, wn = (w & 1) * 64;

    const int rr = tid >> 2, c0 = tid & 3;
    const int sw0 = ((c0       ^ (rr & 7)) << 3);
    const int sw1 = (((c0 + 4) ^ (rr & 7)) << 3);

    const bf16_t* pi[2]; const bf16_t* pj[2];
#pragma unroll
    for (int r = 0; r < 2; ++r) {
        int m = row0 + rr + r * 64;
        pi[r] = XE + (size_t)i_idx[m] * D_DIM + c0 * 8;
        pj[r] = XE + (size_t)j_idx[m] * D_DIM - D_DIM + c0 * 8;  // k in [1024,2048)
    }
    const bf16_t* brow[2];
#pragma unroll
    for (int r = 0; r < 2; ++r)
        brow[r] = W1T + (size_t)(col0 + rr + r * 64) * (2 * D_DIM) + c0 * 8;

    f4v acc[4][4];
#pragma unroll
    for (int i = 0; i < 4; ++i)
#pragma unroll
        for (int jj = 0; jj < 4; ++jj) acc[i][jj] = (f4v)0.f;

    s8v a00, a01, a10, a11, b00, b01, b10, b11;
    const int r7 = t16 & 7;

#define MLP_LOAD(kn_)                                                         \
    {   const int kn = (kn_);                                                 \
        const bf16_t* A0 = (kn < D_DIM) ? pi[0] : pj[0];                      \
        const bf16_t* A1 = (kn < D_DIM) ? pi[1] : pj[1];                      \
        a00 = *(const s8v*)(A0 + kn);                                         \
        a01 = *(const s8v*)(A0 + kn + 32);                                    \
        a10 = *(const s8v*)(A1 + kn);                                         \
        a11 = *(const s8v*)(A1 + kn + 32);                                    \
        b00 = *(const s8v*)(brow[0] + kn);                                    \
        b01 = *(const s8v*)(brow[0] + kn + 32);                               \
        b10 = *(const s8v*)(brow[1] + kn);                                    \
        b11 = *(const s8v*)(brow[1] + kn + 32);                               \
    }
#define MLP_WRITE(buf)                                                        \
    {   bf16_t* Aw = As + (buf) * 8192; bf16_t* Bw = Bs + (buf) * 8192;       \
        *(s8v*)&Aw[rr * 64 + sw0]        = a00;                               \
        *(s8v*)&Aw[rr * 64 + sw1]        = a01;                               \
        *(s8v*)&Aw[(rr + 64) * 64 + sw0] = a10;                               \
        *(s8v*)&Aw[(rr + 64) * 64 + sw1] = a11;                               \
        *(s8v*)&Bw[rr * 64 + sw0]        = b00;                               \
        *(s8v*)&Bw[rr * 64 + sw1]        = b01;                               \
        *(s8v*)&Bw[(rr + 64) * 64 + sw0] = b10;                               \
        *(s8v*)&Bw[(rr + 64) * 64 + sw1] = b11;                               \
    }

    MLP_LOAD(0);
    MLP_WRITE(0);
    MLP_LOAD(64);
    __syncthreads();

    for (int c = 0; c < 32; ++c) {
        const bf16_t* Ar = As + (c & 1) * 8192;
        const bf16_t* Br = Bs + (c & 1) * 8192;
#pragma unroll
        for (int sub = 0; sub < 2; ++sub) {
            const int rsl = (((sub * 4 + q) ^ r7) << 3);
            s8v af[4], bfr[4];
#pragma unroll
            for (int ti = 0; ti < 4; ++ti)
                af[ti] = *(const s8v*)&Ar[(wm + ti * 16 + t16) * 64 + rsl];
#pragma unroll
            for (int tj = 0; tj < 4; ++tj)
                bfr[tj] = *(const s8v*)&Br[(wn + tj * 16 + t16) * 64 + rsl];
#pragma unroll
            for (int ti = 0; ti < 4; ++ti)
#pragma unroll
                for (int tj = 0; tj < 4; ++tj)
                    acc[ti][tj] = mfma16(af[ti], bfr[tj], acc[ti][tj]);
        }
        if (c < 31) MLP_WRITE((c + 1) & 1);    // chunk c+1 regs -> other buffer
        if (c < 30) MLP_LOAD((c + 2) * 64);    // issue chunk c+2
        __syncthreads();
    }
#undef MLP_LOAD
#undef MLP_WRITE

    // fused epilogue in C-layout: fast_tanh, dot with gathered rule row, 16-lane reduce
    const int cb = colTile * 2 + (w & 1);
#pragma unroll
    for (int ti = 0; ti < 4; ++ti) {
#pragma unroll
        for (int rg = 0; rg < 4; ++rg) {
            int m = row0 + wm + ti * 16 + q * 4 + rg;
            int r = r_idx[m];
            const bf16_t* wrow = Wt2 + (size_t)r * D_DIM + col0 + wn + t16;
            float pd = 0.f;
#pragma unroll
            for (int tj = 0; tj < 4; ++tj) {
                int col = col0 + wn + tj * 16 + t16;
                float h = fast_tanh(acc[ti][tj][rg] + b1[col]);
                pd += h * bf2f(wrow[tj * 16]);
            }
            pd += __shfl_xor(pd, 1);
            pd += __shfl_xor(pd, 2);
            pd += __shfl_xor(pd, 4);
            pd += __shfl_xor(pd, 8);
            if (t16 == 0)
                partials[(size_t)cb * M_NODES + m] = pd;
        }
    }
}

// ---------------------------------------------------------------------------
__global__ __launch_bounds__(256) void k_reduce(
    const float* __restrict__ partials, const int* __restrict__ r_idx,
    const float* __restrict__ b2, float* __restrict__ out)
{
    int m = blockIdx.x * 256 + threadIdx.x;
    float s = 0.f;
#pragma unroll
    for (int cb = 0; cb < 16; ++cb)
        s += partials[(size_t)cb * M_NODES + m];
    out[m] = s + b2[r_idx[m]];
}

// ---------------------------------------------------------------------------
extern "C" void kernel_launch(void* const* d_in, const int* in_sizes, int n_in,
                              void* d_out, int out_size, void* d_ws, size_t ws_size,
                              hipStream_t stream) {
    const int*   tokens = (const int*)  d_in[0];
    const int*   i_idx  = (const int*)  d_in[1];
    const int*   j_idx  = (const int*)  d_in[2];
    const int*   r_idx  = (const int*)  d_in[3];
    const float* emb    = (const float*)d_in[4];
    const float* Wxh    = (const float*)d_in[5];
    const float* Whh    = (const float*)d_in[6];
    const float* bh     = (const float*)d_in[7];
    const float* h0     = (const float*)d_in[8];
    const float* W1     = (const float*)d_in[9];
    const float* b1     = (const float*)d_in[10];
    const float* W2     = (const float*)d_in[11];
    const float* b2     = (const float*)d_in[12];
    float* out = (float*)d_out;

    // Workspace (~156 MiB). embB (20 MiB) aliases WhhT/W1T/Wt2 (22 MiB):
    // embB dead after k_xw_mfma; those conversions run after it.
    bf16_t* XE   = (bf16_t*)d_ws;                        // [B*L][D]  128 MiB
    bf16_t* WxhT = XE   + (size_t)M_NODES * D_DIM;       // [D][D]      2 MiB
    bf16_t* WhhT = WxhT + (size_t)D_DIM * D_DIM;         // [D][D]      2 MiB
    bf16_t* W1T  = WhhT + (size_t)D_DIM * D_DIM;         // [D][2D]     4 MiB
    bf16_t* Wt2  = W1T  + (size_t)2 * D_DIM * D_DIM;     // [R][D]     16 MiB
    bf16_t* embB = WhhT;                                 // [V][D]     20 MiB (alias)
    bf16_t* h0b  = Wt2  + (size_t)R_RULES * D_DIM;       // [D] (pad 2048)
    float*  par  = (float*)(h0b + 2048);                 // [16][M]     4 MiB

    // Phase 1: emb->bf16, Wxh, h0
    k_cvt_emb<<<V_VOCAB * D_DIM / 2048, 256, 0, stream>>>(emb, embB);
    k_transcvt<<<dim3(D_DIM / 32, D_DIM / 32), dim3(32, 8), 0, stream>>>(Wxh, WxhT, D_DIM, D_DIM);
    k_cvt_h0<<<1, 256, 0, stream>>>(h0, h0b);

    // Phase 2: XE = bf16(embB[tokens] @ Wxh + bh)   (last reader of embB)
    k_xw_mfma<<<4096, 256, 0, stream>>>(tokens, embB, WxhT, bh, XE);

    // Phase 3: remaining weight conversions (overwrite embB region)
    k_transcvt<<<dim3(D_DIM / 32, D_DIM / 32), dim3(32, 8), 0, stream>>>(Whh, WhhT, D_DIM, D_DIM);
    k_transcvt<<<dim3(D_DIM / 32, 2 * D_DIM / 32), dim3(32, 8), 0, stream>>>(W1, W1T, 2 * D_DIM, D_DIM);
    k_transcvt<<<dim3(R_RULES / 32, D_DIM / 32), dim3(32, 8), 0, stream>>>(W2, Wt2, D_DIM, R_RULES);

    // Phase 4: 64 sequential RNN steps (in-place on XE)
    for (int t = 0; t < L_SEQ; ++t) {
        const bf16_t* Abase = (t == 0) ? h0b : (XE + (size_t)(t - 1) * D_DIM);
        int strideRow       = (t == 0) ? 0   : L_SEQ * D_DIM;
        k_step_mfma<<<dim3(B_BATCH / 64, D_DIM / 64), 256, 0, stream>>>(
            Abase, strideRow, WhhT, XE, t);
    }

    // Phase 5: MLP + fused rule-dot partials
    k_mlp_mfma<<<4096, 256, 0, stream>>>(
        i_idx, j_idx, XE, W1T, b1, Wt2, r_idx, par);

    // Phase 6: deterministic reduce + b2
    k_reduce<<<M_NODES / 256, 256, 0, stream>>>(par, r_idx, b2, out);
}

// Round 7
// 1084.691 us; speedup vs baseline: 1.1049x; 1.0166x over previous
//
#include <hip/hip_runtime.h>

// V=10000, R=8192, D=1024, B=1024, L=64, M=65536
// R16: k_xw/k_mlp reverted to EXACT R12 (best measured: 1069; four k_mlp
// variants since -- depth-2, dbuf, load placement -- all 371-393us/31%
// MfmaUtil: the 128^2+2-barrier family is exhausted, 8-phase rewrite queued).
// RNN fix (lowest-risk, biggest block ~490us): R12 k_step ran 256 blocks =
// 1 block/CU = 1 wave/SIMD -> ZERO TLP, every barrier/latency stall exposed.
// Re-tiled to 32x64 -> 512 blocks = 2 blocks/CU (__launch_bounds__(256,2),
// 21KB LDS), same 2-barrier BK=64 swizzled structure + R13-verified 16x32
// wave epilogue. Predicted: ~7.7 -> ~5us/step, RNN -> ~330, total ~920.
#define D_DIM   1024
#define L_SEQ   64
#define B_BATCH 1024
#define M_NODES 65536
#define R_RULES 8192
#define V_VOCAB 10000

typedef unsigned short bf16_t;
typedef __attribute__((ext_vector_type(8))) short s8v;   // 8 bf16 (MFMA A/B frag)
typedef __attribute__((ext_vector_type(4))) short s4v;   // 4 bf16
typedef __attribute__((ext_vector_type(4))) float f4v;   // MFMA C/D frag

static __device__ __forceinline__ float bf2f(unsigned short u) {
    union { unsigned int i; float f; } v; v.i = ((unsigned int)u) << 16; return v.f;
}
static __device__ __forceinline__ unsigned short f2bf(float f) {  // RNE
    union { float f; unsigned int i; } v; v.f = f;
    return (unsigned short)((v.i + 0x7FFFu + ((v.i >> 16) & 1u)) >> 16);
}
static __device__ __forceinline__ float fast_tanh(float x) {
    float xc = fminf(fmaxf(x, -15.f), 15.f);
    float t  = __expf(2.f * xc);
    return (t - 1.f) * __builtin_amdgcn_rcpf(t + 1.f);
}

static __device__ __forceinline__ f4v mfma16(s8v a, s8v b, f4v c) {
    return __builtin_amdgcn_mfma_f32_16x16x32_bf16(a, b, c, 0, 0, 0);
}

// ---------------------------------------------------------------------------
__global__ __launch_bounds__(256) void k_cvt_emb(
    const float* __restrict__ emb, bf16_t* __restrict__ embB)
{
    size_t i = ((size_t)blockIdx.x * 256 + threadIdx.x) * 8;
    f4v x0 = *(const f4v*)&emb[i];
    f4v x1 = *(const f4v*)&emb[i + 4];
    s8v o;
    o[0] = (short)f2bf(x0.x); o[1] = (short)f2bf(x0.y);
    o[2] = (short)f2bf(x0.z); o[3] = (short)f2bf(x0.w);
    o[4] = (short)f2bf(x1.x); o[5] = (short)f2bf(x1.y);
    o[6] = (short)f2bf(x1.z); o[7] = (short)f2bf(x1.w);
    *(s8v*)&embB[i] = o;
}

__global__ __launch_bounds__(256) void k_transcvt(
    const float* __restrict__ src, bf16_t* __restrict__ dst, int K, int N)
{
    __shared__ float s[32][33];
    int n0 = blockIdx.x * 32, k0 = blockIdx.y * 32;
    int tx = threadIdx.x, ty = threadIdx.y;  // (32,8)
#pragma unroll
    for (int i = 0; i < 4; ++i)
        s[ty + i * 8][tx] = src[(size_t)(k0 + ty + i * 8) * N + n0 + tx];
    __syncthreads();
#pragma unroll
    for (int i = 0; i < 4; ++i)
        dst[(size_t)(n0 + ty + i * 8) * K + k0 + tx] = f2bf(s[tx][ty + i * 8]);
}

__global__ __launch_bounds__(256) void k_cvt_h0(
    const float* __restrict__ h0, bf16_t* __restrict__ h0b)
{
    for (int u = threadIdx.x; u < D_DIM; u += 256) h0b[u] = f2bf(h0[u]);
}

// ---------------------------------------------------------------------------
// k_xw_mfma: XE[n,:] = bf16(embB[tokens[n],:] @ Wxh + bh)
// 128x128 tile, BK=64, swizzled LDS, depth-1 VGPR prefetch, XCD swizzle.
// (R12 verbatim)
// ---------------------------------------------------------------------------
__global__ __launch_bounds__(256) void k_xw_mfma(
    const int* __restrict__ tokens, const bf16_t* __restrict__ embB,
    const bf16_t* __restrict__ WxhT, const float* __restrict__ bh,
    bf16_t* __restrict__ XE)
{
    __shared__ bf16_t As[128 * 64];            // 16 KB (swizzled 16B slots)
    __shared__ bf16_t Bs[128 * 64];            // 16 KB
    __shared__ float  epi[4][16][68];          // 17.4 KB (per-wave private)

    const int bi  = blockIdx.x;
    const int xcd = bi & 7, j = bi >> 3;
    const int row0 = ((xcd << 6) + (j >> 3)) * 128;   // rowTile in [0,512)
    const int col0 = (j & 7) * 128;                   // colTile in [0,8)

    const int tid = threadIdx.x;
    const int w = tid >> 6, l = tid & 63;
    const int q = l >> 4, t16 = l & 15;
    const int wm = (w >> 1) * 64, wn = (w & 1) * 64;

    const int rr = tid >> 2, c0 = tid & 3;            // staging row / base slot
    const int sw0 = ((c0       ^ (rr & 7)) << 3);     // swizzled slot offsets
    const int sw1 = (((c0 + 4) ^ (rr & 7)) << 3);     // ((rr+64)&7)==(rr&7)

    const bf16_t* arow[2];
#pragma unroll
    for (int r = 0; r < 2; ++r)
        arow[r] = embB + (size_t)tokens[row0 + rr + r * 64] * D_DIM + c0 * 8;
    const bf16_t* brow[2];
#pragma unroll
    for (int r = 0; r < 2; ++r)
        brow[r] = WxhT + (size_t)(col0 + rr + r * 64) * D_DIM + c0 * 8;

    f4v acc[4][4];
#pragma unroll
    for (int i = 0; i < 4; ++i)
#pragma unroll
        for (int jj = 0; jj < 4; ++jj) acc[i][jj] = (f4v)0.f;

    // prefetch chunk 0 (8 x 16B)
    s8v a00 = *(const s8v*)(arow[0]);
    s8v a01 = *(const s8v*)(arow[0] + 32);
    s8v a10 = *(const s8v*)(arow[1]);
    s8v a11 = *(const s8v*)(arow[1] + 32);
    s8v b00 = *(const s8v*)(brow[0]);
    s8v b01 = *(const s8v*)(brow[0] + 32);
    s8v b10 = *(const s8v*)(brow[1]);
    s8v b11 = *(const s8v*)(brow[1] + 32);

    const int r7 = t16 & 7;
    for (int k0 = 0; k0 < D_DIM; k0 += 64) {
        __syncthreads();                       // prev iter frag reads done
        *(s8v*)&As[rr * 64 + sw0]        = a00;
        *(s8v*)&As[rr * 64 + sw1]        = a01;
        *(s8v*)&As[(rr + 64) * 64 + sw0] = a10;
        *(s8v*)&As[(rr + 64) * 64 + sw1] = a11;
        *(s8v*)&Bs[rr * 64 + sw0]        = b00;
        *(s8v*)&Bs[rr * 64 + sw1]        = b01;
        *(s8v*)&Bs[(rr + 64) * 64 + sw0] = b10;
        *(s8v*)&Bs[(rr + 64) * 64 + sw1] = b11;
        int kn = k0 + 64;
        if (kn < D_DIM) {                      // issue next loads
            a00 = *(const s8v*)(arow[0] + kn);
            a01 = *(const s8v*)(arow[0] + kn + 32);
            a10 = *(const s8v*)(arow[1] + kn);
            a11 = *(const s8v*)(arow[1] + kn + 32);
            b00 = *(const s8v*)(brow[0] + kn);
            b01 = *(const s8v*)(brow[0] + kn + 32);
            b10 = *(const s8v*)(brow[1] + kn);
            b11 = *(const s8v*)(brow[1] + kn + 32);
        }
        __syncthreads();
#pragma unroll
        for (int sub = 0; sub < 2; ++sub) {
            const int rsl = (((sub * 4 + q) ^ r7) << 3);
            s8v af[4], bfr[4];
#pragma unroll
            for (int ti = 0; ti < 4; ++ti)
                af[ti] = *(const s8v*)&As[(wm + ti * 16 + t16) * 64 + rsl];
#pragma unroll
            for (int tj = 0; tj < 4; ++tj)
                bfr[tj] = *(const s8v*)&Bs[(wn + tj * 16 + t16) * 64 + rsl];
#pragma unroll
            for (int ti = 0; ti < 4; ++ti)
#pragma unroll
                for (int tj = 0; tj < 4; ++tj)
                    acc[ti][tj] = mfma16(af[ti], bfr[tj], acc[ti][tj]);
        }
    }

    // barrier-free per-wave epilogue (epi[w] wave-private)
    const int lr = l >> 2, c16 = (l & 3) * 16;
    f4v bias[4];
#pragma unroll
    for (int u = 0; u < 4; ++u)
        bias[u] = *(const f4v*)&bh[col0 + wn + c16 + u * 4];
#pragma unroll
    for (int ti = 0; ti < 4; ++ti) {
#pragma unroll
        for (int tj = 0; tj < 4; ++tj)
#pragma unroll
            for (int rg = 0; rg < 4; ++rg)
                epi[w][q * 4 + rg][tj * 16 + t16] = acc[ti][tj][rg];
        s8v o0, o1;
#pragma unroll
        for (int u = 0; u < 8; ++u) {
            o0[u] = (short)f2bf(epi[w][lr][c16 + u]     + bias[u >> 2][u & 3]);
            o1[u] = (short)f2bf(epi[w][lr][c16 + 8 + u] + bias[2 + (u >> 2)][u & 3]);
        }
        size_t orow = (size_t)(row0 + wm + ti * 16 + lr) * D_DIM + col0 + wn + c16;
        *(s8v*)&XE[orow]     = o0;
        *(s8v*)&XE[orow + 8] = o1;
    }
}

// ---------------------------------------------------------------------------
// k_step_mfma (x64): y = tanh(XE[b*L+t,:] + h_prev[b,:] @ Whh); XE[..] = bf16(y)
// 32x64 tile -> 512 blocks = 2 blocks/CU (TLP!), 256 thr, 4 waves as 2x2
// quadrants of 16x32, BK=64, swizzled LDS, depth-1 prefetch, 16B stores.
// ---------------------------------------------------------------------------
__global__ __launch_bounds__(256, 2) void k_step_mfma(
    const bf16_t* __restrict__ Abase, int strideRow,
    const bf16_t* __restrict__ WhhT, bf16_t* __restrict__ XE, int t)
{
    __shared__ bf16_t As[32 * 64];             // 4 KB
    __shared__ bf16_t Bs[64 * 64];             // 8 KB
    __shared__ float  epi[4][16][36];          // 9.2 KB (per-wave private)

    const int tid = threadIdx.x;
    const int w = tid >> 6, l = tid & 63;
    const int q = l >> 4, t16 = l & 15;
    const int wr = w >> 1, wc = w & 1;         // 2x2: 16 rows x 32 cols per wave
    const int row0 = blockIdx.x * 32, col0 = blockIdx.y * 64;

    // A staging: 32 rows x 8 slots, 1 s8v/thread
    const int ar = tid >> 3, ca = tid & 7;
    const int swA = ((ca ^ (ar & 7)) << 3);
    // B staging: 64 rows x 8 slots, 2 s8v/thread
    const int br = tid >> 2, cb = tid & 3;
    const int swB0 = ((cb       ^ (br & 7)) << 3);
    const int swB1 = (((cb + 4) ^ (br & 7)) << 3);

    const bf16_t* asrc = Abase + (size_t)(row0 + ar) * strideRow + ca * 8;
    const bf16_t* bsrc = WhhT + (size_t)(col0 + br) * D_DIM + cb * 8;

    f4v acc[2];
    acc[0] = (f4v)0.f; acc[1] = (f4v)0.f;

    s8v rA  = *(const s8v*)(asrc);
    s8v rB0 = *(const s8v*)(bsrc);
    s8v rB1 = *(const s8v*)(bsrc + 32);

    const int r7 = t16 & 7;
    for (int k0 = 0; k0 < D_DIM; k0 += 64) {
        __syncthreads();                       // prev iter frag reads done
        *(s8v*)&As[ar * 64 + swA]  = rA;
        *(s8v*)&Bs[br * 64 + swB0] = rB0;
        *(s8v*)&Bs[br * 64 + swB1] = rB1;
        int kn = k0 + 64;
        if (kn < D_DIM) {                      // issue next loads
            rA  = *(const s8v*)(asrc + kn);
            rB0 = *(const s8v*)(bsrc + kn);
            rB1 = *(const s8v*)(bsrc + kn + 32);
        }
        __syncthreads();
#pragma unroll
        for (int sub = 0; sub < 2; ++sub) {
            const int rsl = (((sub * 4 + q) ^ r7) << 3);
            s8v af = *(const s8v*)&As[(wr * 16 + t16) * 64 + rsl];
            s8v b0 = *(const s8v*)&Bs[(wc * 32 + t16) * 64 + rsl];
            s8v b1 = *(const s8v*)&Bs[(wc * 32 + 16 + t16) * 64 + rsl];
            acc[0] = mfma16(af, b0, acc[0]);
            acc[1] = mfma16(af, b1, acc[1]);
        }
    }

    // per-wave epilogue, no barriers: 16 rows x 32 cols per wave (R13-verified)
    const int lr = l >> 2, c8 = (l & 3) * 8;
#pragma unroll
    for (int tj = 0; tj < 2; ++tj)
#pragma unroll
        for (int rg = 0; rg < 4; ++rg)
            epi[w][q * 4 + rg][tj * 16 + t16] = acc[tj][rg];
    f4v v0 = *(const f4v*)&epi[w][lr][c8];
    f4v v1 = *(const f4v*)&epi[w][lr][c8 + 4];
    int b = row0 + wr * 16 + lr;
    size_t xi = ((size_t)b * L_SEQ + t) * D_DIM + col0 + wc * 32 + c8;
    s8v x = *(const s8v*)&XE[xi];
    s8v o;
#pragma unroll
    for (int u = 0; u < 4; ++u) {
        o[u]     = (short)f2bf(fast_tanh(bf2f((unsigned short)x[u])     + v0[u]));
        o[u + 4] = (short)f2bf(fast_tanh(bf2f((unsigned short)x[u + 4]) + v1[u]));
    }
    *(s8v*)&XE[xi] = o;
}

// ---------------------------------------------------------------------------
// k_mlp_mfma: h = tanh(concat(XE[i],XE[j]) @ W1 + b1) fused with rule-dot.
// 128x128 tile, K=2048, BK=64, swizzled LDS, depth-1 prefetch, XCD swizzle.
// (R12 verbatim)
// ---------------------------------------------------------------------------
__global__ __launch_bounds__(256) void k_mlp_mfma(
    const int* __restrict__ i_idx, const int* __restrict__ j_idx,
    const bf16_t* __restrict__ XE, const bf16_t* __restrict__ W1T,
    const float* __restrict__ b1, const bf16_t* __restrict__ Wt2,
    const int* __restrict__ r_idx, float* __restrict__ partials)
{
    __shared__ bf16_t As[128 * 64];            // 16 KB
    __shared__ bf16_t Bs[128 * 64];            // 16 KB

    const int bi  = blockIdx.x;
    const int xcd = bi & 7, j = bi >> 3;
    const int rowTile = (xcd << 6) + (j >> 3);        // [0,512)
    const int colTile = j & 7;                        // [0,8)
    const int row0 = rowTile * 128, col0 = colTile * 128;

    const int tid = threadIdx.x;
    const int w = tid >> 6, l = tid & 63;
    const int q = l >> 4, t16 = l & 15;
    const int wm = (w >> 1) * 64, wn = (w & 1) * 64;

    const int rr = tid >> 2, c0 = tid & 3;
    const int sw0 = ((c0       ^ (rr & 7)) << 3);
    const int sw1 = (((c0 + 4) ^ (rr & 7)) << 3);

    const bf16_t* pi[2]; const bf16_t* pj[2];
#pragma unroll
    for (int r = 0; r < 2; ++r) {
        int m = row0 + rr + r * 64;
        pi[r] = XE + (size_t)i_idx[m] * D_DIM + c0 * 8;
        pj[r] = XE + (size_t)j_idx[m] * D_DIM - D_DIM + c0 * 8;  // k in [1024,2048)
    }
    const bf16_t* brow[2];
#pragma unroll
    for (int r = 0; r < 2; ++r)
        brow[r] = W1T + (size_t)(col0 + rr + r * 64) * (2 * D_DIM) + c0 * 8;

    f4v acc[4][4];
#pragma unroll
    for (int i = 0; i < 4; ++i)
#pragma unroll
        for (int jj = 0; jj < 4; ++jj) acc[i][jj] = (f4v)0.f;

    // prefetch chunk 0
    s8v a00 = *(const s8v*)(pi[0]);
    s8v a01 = *(const s8v*)(pi[0] + 32);
    s8v a10 = *(const s8v*)(pi[1]);
    s8v a11 = *(const s8v*)(pi[1] + 32);
    s8v b00 = *(const s8v*)(brow[0]);
    s8v b01 = *(const s8v*)(brow[0] + 32);
    s8v b10 = *(const s8v*)(brow[1]);
    s8v b11 = *(const s8v*)(brow[1] + 32);

    const int r7 = t16 & 7;
    for (int k0 = 0; k0 < 2 * D_DIM; k0 += 64) {
        __syncthreads();
        *(s8v*)&As[rr * 64 + sw0]        = a00;
        *(s8v*)&As[rr * 64 + sw1]        = a01;
        *(s8v*)&As[(rr + 64) * 64 + sw0] = a10;
        *(s8v*)&As[(rr + 64) * 64 + sw1] = a11;
        *(s8v*)&Bs[rr * 64 + sw0]        = b00;
        *(s8v*)&Bs[rr * 64 + sw1]        = b01;
        *(s8v*)&Bs[(rr + 64) * 64 + sw0] = b10;
        *(s8v*)&Bs[(rr + 64) * 64 + sw1] = b11;
        int kn = k0 + 64;
        if (kn < 2 * D_DIM) {
            const bf16_t* A0 = (kn < D_DIM) ? pi[0] : pj[0];
            const bf16_t* A1 = (kn < D_DIM) ? pi[1] : pj[1];
            a00 = *(const s8v*)(A0 + kn);
            a01 = *(const s8v*)(A0 + kn + 32);
            a10 = *(const s8v*)(A1 + kn);
            a11 = *(const s8v*)(A1 + kn + 32);
            b00 = *(const s8v*)(brow[0] + kn);
            b01 = *(const s8v*)(brow[0] + kn + 32);
            b10 = *(const s8v*)(brow[1] + kn);
            b11 = *(const s8v*)(brow[1] + kn + 32);
        }
        __syncthreads();
#pragma unroll
        for (int sub = 0; sub < 2; ++sub) {
            const int rsl = (((sub * 4 + q) ^ r7) << 3);
            s8v af[4], bfr[4];
#pragma unroll
            for (int ti = 0; ti < 4; ++ti)
                af[ti] = *(const s8v*)&As[(wm + ti * 16 + t16) * 64 + rsl];
#pragma unroll
            for (int tj = 0; tj < 4; ++tj)
                bfr[tj] = *(const s8v*)&Bs[(wn + tj * 16 + t16) * 64 + rsl];
#pragma unroll
            for (int ti = 0; ti < 4; ++ti)
#pragma unroll
                for (int tj = 0; tj < 4; ++tj)
                    acc[ti][tj] = mfma16(af[ti], bfr[tj], acc[ti][tj]);
        }
    }

    // fused epilogue in C-layout: fast_tanh, dot with gathered rule row, 16-lane reduce
    const int cb = colTile * 2 + (w & 1);
#pragma unroll
    for (int ti = 0; ti < 4; ++ti) {
#pragma unroll
        for (int rg = 0; rg < 4; ++rg) {
            int m = row0 + wm + ti * 16 + q * 4 + rg;
            int r = r_idx[m];
            const bf16_t* wrow = Wt2 + (size_t)r * D_DIM + col0 + wn + t16;
            float pd = 0.f;
#pragma unroll
            for (int tj = 0; tj < 4; ++tj) {
                int col = col0 + wn + tj * 16 + t16;
                float h = fast_tanh(acc[ti][tj][rg] + b1[col]);
                pd += h * bf2f(wrow[tj * 16]);
            }
            pd += __shfl_xor(pd, 1);
            pd += __shfl_xor(pd, 2);
            pd += __shfl_xor(pd, 4);
            pd += __shfl_xor(pd, 8);
            if (t16 == 0)
                partials[(size_t)cb * M_NODES + m] = pd;
        }
    }
}

// ---------------------------------------------------------------------------
__global__ __launch_bounds__(256) void k_reduce(
    const float* __restrict__ partials, const int* __restrict__ r_idx,
    const float* __restrict__ b2, float* __restrict__ out)
{
    int m = blockIdx.x * 256 + threadIdx.x;
    float s = 0.f;
#pragma unroll
    for (int cb = 0; cb < 16; ++cb)
        s += partials[(size_t)cb * M_NODES + m];
    out[m] = s + b2[r_idx[m]];
}

// ---------------------------------------------------------------------------
extern "C" void kernel_launch(void* const* d_in, const int* in_sizes, int n_in,
                              void* d_out, int out_size, void* d_ws, size_t ws_size,
                              hipStream_t stream) {
    const int*   tokens = (const int*)  d_in[0];
    const int*   i_idx  = (const int*)  d_in[1];
    const int*   j_idx  = (const int*)  d_in[2];
    const int*   r_idx  = (const int*)  d_in[3];
    const float* emb    = (const float*)d_in[4];
    const float* Wxh    = (const float*)d_in[5];
    const float* Whh    = (const float*)d_in[6];
    const float* bh     = (const float*)d_in[7];
    const float* h0     = (const float*)d_in[8];
    const float* W1     = (const float*)d_in[9];
    const float* b1     = (const float*)d_in[10];
    const float* W2     = (const float*)d_in[11];
    const float* b2     = (const float*)d_in[12];
    float* out = (float*)d_out;

    // Workspace (~156 MiB). embB (20 MiB) aliases WhhT/W1T/Wt2 (22 MiB):
    // embB dead after k_xw_mfma; those conversions run after it.
    bf16_t* XE   = (bf16_t*)d_ws;                        // [B*L][D]  128 MiB
    bf16_t* WxhT = XE   + (size_t)M_NODES * D_DIM;       // [D][D]      2 MiB
    bf16_t* WhhT = WxhT + (size_t)D_DIM * D_DIM;         // [D][D]      2 MiB
    bf16_t* W1T  = WhhT + (size_t)D_DIM * D_DIM;         // [D][2D]     4 MiB
    bf16_t* Wt2  = W1T  + (size_t)2 * D_DIM * D_DIM;     // [R][D]     16 MiB
    bf16_t* embB = WhhT;                                 // [V][D]     20 MiB (alias)
    bf16_t* h0b  = Wt2  + (size_t)R_RULES * D_DIM;       // [D] (pad 2048)
    float*  par  = (float*)(h0b + 2048);                 // [16][M]     4 MiB

    // Phase 1: emb->bf16, Wxh, h0
    k_cvt_emb<<<V_VOCAB * D_DIM / 2048, 256, 0, stream>>>(emb, embB);
    k_transcvt<<<dim3(D_DIM / 32, D_DIM / 32), dim3(32, 8), 0, stream>>>(Wxh, WxhT, D_DIM, D_DIM);
    k_cvt_h0<<<1, 256, 0, stream>>>(h0, h0b);

    // Phase 2: XE = bf16(embB[tokens] @ Wxh + bh)   (last reader of embB)
    k_xw_mfma<<<4096, 256, 0, stream>>>(tokens, embB, WxhT, bh, XE);

    // Phase 3: remaining weight conversions (overwrite embB region)
    k_transcvt<<<dim3(D_DIM / 32, D_DIM / 32), dim3(32, 8), 0, stream>>>(Whh, WhhT, D_DIM, D_DIM);
    k_transcvt<<<dim3(D_DIM / 32, 2 * D_DIM / 32), dim3(32, 8), 0, stream>>>(W1, W1T, 2 * D_DIM, D_DIM);
    k_transcvt<<<dim3(R_RULES / 32, D_DIM / 32), dim3(32, 8), 0, stream>>>(W2, Wt2, D_DIM, R_RULES);

    // Phase 4: 64 sequential RNN steps (in-place on XE)
    for (int t = 0; t < L_SEQ; ++t) {
        const bf16_t* Abase = (t == 0) ? h0b : (XE + (size_t)(t - 1) * D_DIM);
        int strideRow       = (t == 0) ? 0   : L_SEQ * D_DIM;
        k_step_mfma<<<dim3(B_BATCH / 32, D_DIM / 64), 256, 0, stream>>>(
            Abase, strideRow, WhhT, XE, t);
    }

    // Phase 5: MLP + fused rule-dot partials
    k_mlp_mfma<<<4096, 256, 0, stream>>>(
        i_idx, j_idx, XE, W1T, b1, Wt2, r_idx, par);

    // Phase 6: deterministic reduce + b2
    k_reduce<<<M_NODES / 256, 256, 0, stream>>>(par, r_idx, b2, out);
}